// Round 1
// baseline (116.810 us; speedup 1.0000x reference)
//
#include <hip/hip_runtime.h>
#include <cmath>

#define C_COLS 8192

typedef float f4 __attribute__((ext_vector_type(4)));

struct NfArgs {
    float tbl[16];   // fp16-exact NF4 levels, as f32
    float kexp;      // -1.702 * log2(e) * qmax  (logistic index estimate)
};

// ---------------------------------------------------------------------------
// One workgroup (256 thr = 4 waves) per row; wave w owns floats
// [w*2048, w*2048+2048); load k: lane holds float4 at elem 256k+4*lane; each
// 16-lane group holds one contiguous 64-elem quant-block.
//
// Decision arithmetic is BIT-IDENTICAL to the passing R5/R6 kernel:
//   x_norm: s2r = 2.0f/den; p=(x-bm)*s2r; xn=p-1.0f (separate sub, no fma)
//   argmin: logistic index estimate c, clamp [1,14], exact 3-candidate
//           strict-'<' replay in index order (ties identical to full scan)
//   scales: recip-hoisted (sc-s_min)*round32(1/sden)*255, rintf (RNE)
//
// This round: nontemporal load/store (once-streamed data, skip cache
// retention/write-allocate), and register slimming: srec[] gone (folded into
// the output loop), bmax[] replaced by sc[]=bmax-bmin (computed pre-barrier
// with the identical expression, so all downstream values are bit-identical).
// ---------------------------------------------------------------------------
__global__ __launch_bounds__(256) void nf4_main_kernel(
        const float* __restrict__ x, float* __restrict__ out, NfArgs args) {
#pragma clang fp contract(off)
    __shared__ float stbl[16];
    __shared__ float smin[4], smax[4];

    const int row  = blockIdx.x;
    const int wave = threadIdx.x >> 6;
    const int lane = threadIdx.x & 63;
    const long base = (long)row * C_COLS + (long)wave * 2048;
    const f4* __restrict__ xin4 = reinterpret_cast<const f4*>(x + base);
    f4* __restrict__ out4       = reinterpret_cast<f4*>(out + base);

    // issue all global loads first (8 outstanding dwordx4 per lane), NT hint:
    // input is touched exactly once — don't retain lines in L2/LLC.
    f4 v[8];
#pragma unroll
    for (int k = 0; k < 8; ++k)
        v[k] = __builtin_nontemporal_load(&xin4[k * 64 + lane]);   // coalesced

    if (threadIdx.x < 16) stbl[threadIdx.x] = args.tbl[threadIdx.x];

    // ---- block min/max (16-lane group = one 64-elem quant-block) ----
    float bmin[8], bsc[8];
    float tmin = 3.4e38f, tmax = -3.4e38f;
#pragma unroll
    for (int k = 0; k < 8; ++k) {
        float m = fminf(fminf(v[k].x, v[k].y), fminf(v[k].z, v[k].w));
        float M = fmaxf(fmaxf(v[k].x, v[k].y), fmaxf(v[k].z, v[k].w));
#pragma unroll
        for (int off = 1; off < 16; off <<= 1) {
            m = fminf(m, __shfl_xor(m, off));
            M = fmaxf(M, __shfl_xor(M, off));
        }
        bmin[k] = m;
        float sc = M - m;                              // exact, same expr as R5
        bsc[k]  = sc;
        tmin = fminf(tmin, sc);
        tmax = fmaxf(tmax, sc);
    }
    tmin = fminf(tmin, __shfl_xor(tmin, 16));
    tmin = fminf(tmin, __shfl_xor(tmin, 32));
    tmax = fmaxf(tmax, __shfl_xor(tmax, 16));
    tmax = fmaxf(tmax, __shfl_xor(tmax, 32));

    if (lane == 0) { smin[wave] = tmin; smax[wave] = tmax; }
    __syncthreads();                                   // covers stbl + smin/smax

    const float s_min  = fminf(fminf(smin[0], smin[1]), fminf(smin[2], smin[3]));
    const float s_max  = fmaxf(fmaxf(smax[0], smax[1]), fmaxf(smax[2], smax[3]));
    const float srange = s_max - s_min;
    const float sden   = srange + 1e-8f;
    const float sqr    = 1.0f / sden;                  // broadcast recip hoist

    const float kexp = args.kexp;
#pragma unroll
    for (int k = 0; k < 8; ++k) {
        const float bm  = bmin[k];
        const float sc  = bsc[k];
        const float den = sc + 1e-8f;                  // == (bmax-bm)+1e-8, exact
        const float s2r = 2.0f / den;
        // double-quant scale reconstruction (identical math, now inline)
        const float sq = rintf(((sc - s_min) * sqr) * 255.0f);   // RNE = np.round
        const float sr = s_min + sq / 255.0f * srange;
        float xv[4] = { v[k].x, v[k].y, v[k].z, v[k].w };
        float wv[4];
#pragma unroll
        for (int c = 0; c < 4; ++c) {
            // exact R5 x_norm: recip-mul then SEPARATE subtract (no fma)
            float p  = (xv[c] - bm) * s2r;
            float xn = p - 1.0f;
            // --- index estimate: 16*logistic(1.702*z), z = xn*qmax ---
            float eb = __builtin_amdgcn_exp2f(xn * kexp);
            float f  = 16.0f * __builtin_amdgcn_rcpf(1.0f + eb);
            int ci = (int)f;                           // f in [0,16) -> trunc
            ci = min(max(ci, 1), 14);
            // --- 3-candidate exact replay of the R5 scan ---
            float tm1 = stbl[ci - 1];
            float tc  = stbl[ci];
            float tp1 = stbl[ci + 1];
            float a0 = fabsf(xn - tm1);
            float a1 = fabsf(xn - tc);
            float a2 = fabsf(xn - tp1);
            float t01  = (a1 < a0) ? tc : tm1;         // strict <, index order
            float amin = fminf(a1, a0);
            float tsel = (a2 < amin) ? tp1 : t01;
            wv[c] = (tsel + 1.0f) * 0.5f * sr + bm;    // mul+add, contract off
        }
        f4 r; r.x = wv[0]; r.y = wv[1]; r.z = wv[2]; r.w = wv[3];
        // output is written once and never re-read by us — NT store skips
        // write-allocate retention in L2/LLC.
        __builtin_nontemporal_store(r, &out4[k * 64 + lane]);
    }
}

// ---------------------------------------------------------------------------
// Host-side table computation (input-independent, deterministic): f64 ndtri
// via A&S seed + 3 Newton steps on Phi (converges ~1e-13 -> f32 cast is
// libm-variation-proof), f32 normalize, exact fp16 RNE via ulp-scaled rint.
// Same values the passing R5/R6 device path produced.
// ---------------------------------------------------------------------------
static void compute_nf_args(NfArgs* a) {
    double z[16];
    for (int i = 0; i < 16; ++i) {
        double p  = (2.0 * i + 1.0) / 32.0;
        double pl = (p < 0.5) ? p : 1.0 - p;
        double t  = std::sqrt(-2.0 * std::log(pl));
        double zz = t - (2.30753 + 0.27061 * t) / (1.0 + t * (0.99229 + 0.04481 * t));
        if (p < 0.5) zz = -zz;
        for (int it = 0; it < 3; ++it) {
            double Phi = 0.5 * std::erfc(-zz * 0.7071067811865476);
            double phi = 0.3989422804014326779 * std::exp(-0.5 * zz * zz);
            zz -= (Phi - p) / phi;
        }
        z[i] = zz;
    }
    float zf[16], qmax = 0.0f;
    for (int i = 0; i < 16; ++i) { zf[i] = (float)z[i]; qmax = std::fmax(qmax, std::fabs(zf[i])); }
    for (int i = 0; i < 16; ++i) {
        float qn = zf[i] / qmax;                       // IEEE f32 divide
        // exact f32 -> fp16 RNE (values are normal-range fp16)
        double av = std::fabs((double)qn);
        int e; std::frexp(av, &e);
        double ulp = std::ldexp(1.0, e - 11);
        a->tbl[i] = (float)std::copysign(std::rint(av / ulp) * ulp, (double)qn);
    }
    a->kexp = (float)(-1.702 * 1.4426950408889634 * (double)qmax);
}

extern "C" void kernel_launch(void* const* d_in, const int* in_sizes, int n_in,
                              void* d_out, int out_size, void* d_ws, size_t ws_size,
                              hipStream_t stream) {
    const float* x = (const float*)d_in[0];
    float* out     = (float*)d_out;
    const int rows = in_sizes[0] / C_COLS;

    NfArgs args;
    compute_nf_args(&args);                            // host CPU, ~µs, deterministic

    nf4_main_kernel<<<rows, 256, 0, stream>>>(x, out, args);
}

// Round 2
// 106.793 us; speedup vs baseline: 1.0938x; 1.0938x over previous
//
#include <hip/hip_runtime.h>
#include <cmath>

#define C_COLS 8192

typedef float f4 __attribute__((ext_vector_type(4)));

struct NfArgs {
    float tbl[16];   // fp16-exact NF4 levels, as f32
    float kexp;      // -1.702 * log2(e) * qmax  (logistic index estimate)
};

// ---------------------------------------------------------------------------
// One workgroup (256 thr = 4 waves) per row; wave w owns floats
// [w*2048, w*2048+2048); load k: lane holds float4 at elem 256k+4*lane; each
// 16-lane group holds one contiguous 64-elem quant-block.
//
// Decision arithmetic is BIT-IDENTICAL to the passing R5/R6 kernel:
//   x_norm: s2r = 2.0f/den; p=(x-bm)*s2r; xn=p-1.0f (separate sub, no fma)
//   argmin: logistic index estimate c, clamp [1,14], exact 3-candidate
//           strict-'<' replay in index order (ties identical to full scan)
//   scales: recip-hoisted (sc-s_min)*round32(1/sden)*255, rintf (RNE)
//
// This round (schedule fix, no math change): R1's counters showed VGPR=36 —
// the compiler was NOT keeping v[0..7] live across the barrier; it
// single-buffered the loads (no MLP) and rematerialized them in loop 2
// (double read, NT-load made the re-read miss L2). Fix: empty asm with
// "+v" constraints after __syncthreads() pins all 8 float4 in VGPRs — loads
// must be issued up-front and held, single-pass streaming restored. NT load
// dropped (input read once; plain load lets LLC-warm lines serve); NT store
// kept (output write-once, never re-read).
// ---------------------------------------------------------------------------
__global__ __launch_bounds__(256) void nf4_main_kernel(
        const float* __restrict__ x, float* __restrict__ out, NfArgs args) {
#pragma clang fp contract(off)
    __shared__ float stbl[16];
    __shared__ float smin[4], smax[4];

    const int row  = blockIdx.x;
    const int wave = threadIdx.x >> 6;
    const int lane = threadIdx.x & 63;
    const long base = (long)row * C_COLS + (long)wave * 2048;
    const f4* __restrict__ xin4 = reinterpret_cast<const f4*>(x + base);
    f4* __restrict__ out4       = reinterpret_cast<f4*>(out + base);

    // issue all global loads first (8 outstanding dwordx4 per lane)
    f4 v[8];
#pragma unroll
    for (int k = 0; k < 8; ++k) v[k] = xin4[k * 64 + lane];   // coalesced

    if (threadIdx.x < 16) stbl[threadIdx.x] = args.tbl[threadIdx.x];

    // ---- block min/max (16-lane group = one 64-elem quant-block) ----
    float bmin[8], bsc[8];
    float tmin = 3.4e38f, tmax = -3.4e38f;
#pragma unroll
    for (int k = 0; k < 8; ++k) {
        float m = fminf(fminf(v[k].x, v[k].y), fminf(v[k].z, v[k].w));
        float M = fmaxf(fmaxf(v[k].x, v[k].y), fmaxf(v[k].z, v[k].w));
#pragma unroll
        for (int off = 1; off < 16; off <<= 1) {
            m = fminf(m, __shfl_xor(m, off));
            M = fmaxf(M, __shfl_xor(M, off));
        }
        bmin[k] = m;
        float sc = M - m;                              // exact, same expr as R5
        bsc[k]  = sc;
        tmin = fminf(tmin, sc);
        tmax = fmaxf(tmax, sc);
    }
    tmin = fminf(tmin, __shfl_xor(tmin, 16));
    tmin = fminf(tmin, __shfl_xor(tmin, 32));
    tmax = fmaxf(tmax, __shfl_xor(tmax, 16));
    tmax = fmaxf(tmax, __shfl_xor(tmax, 32));

    if (lane == 0) { smin[wave] = tmin; smax[wave] = tmax; }
    __syncthreads();                                   // covers stbl + smin/smax

    // Pin the input tile in VGPRs across the barrier: values become asm
    // outputs, so the compiler can no longer rematerialize the global loads
    // in the second loop (which is what produced R1's VGPR=36 / 42.6 us
    // no-MLP schedule). Empty asm — zero runtime cost, unchanged values.
    asm volatile("" : "+v"(v[0]), "+v"(v[1]), "+v"(v[2]), "+v"(v[3]),
                      "+v"(v[4]), "+v"(v[5]), "+v"(v[6]), "+v"(v[7]));

    const float s_min  = fminf(fminf(smin[0], smin[1]), fminf(smin[2], smin[3]));
    const float s_max  = fmaxf(fmaxf(smax[0], smax[1]), fmaxf(smax[2], smax[3]));
    const float srange = s_max - s_min;
    const float sden   = srange + 1e-8f;
    const float sqr    = 1.0f / sden;                  // broadcast recip hoist

    const float kexp = args.kexp;
#pragma unroll
    for (int k = 0; k < 8; ++k) {
        const float bm  = bmin[k];
        const float sc  = bsc[k];
        const float den = sc + 1e-8f;                  // == (bmax-bm)+1e-8, exact
        const float s2r = 2.0f / den;
        // double-quant scale reconstruction (identical math, inline)
        const float sq = rintf(((sc - s_min) * sqr) * 255.0f);   // RNE = np.round
        const float sr = s_min + sq / 255.0f * srange;
        float xv[4] = { v[k].x, v[k].y, v[k].z, v[k].w };
        float wv[4];
#pragma unroll
        for (int c = 0; c < 4; ++c) {
            // exact R5 x_norm: recip-mul then SEPARATE subtract (no fma)
            float p  = (xv[c] - bm) * s2r;
            float xn = p - 1.0f;
            // --- index estimate: 16*logistic(1.702*z), z = xn*qmax ---
            float eb = __builtin_amdgcn_exp2f(xn * kexp);
            float f  = 16.0f * __builtin_amdgcn_rcpf(1.0f + eb);
            int ci = (int)f;                           // f in [0,16) -> trunc
            ci = min(max(ci, 1), 14);
            // --- 3-candidate exact replay of the R5 scan ---
            float tm1 = stbl[ci - 1];
            float tc  = stbl[ci];
            float tp1 = stbl[ci + 1];
            float a0 = fabsf(xn - tm1);
            float a1 = fabsf(xn - tc);
            float a2 = fabsf(xn - tp1);
            float t01  = (a1 < a0) ? tc : tm1;         // strict <, index order
            float amin = fminf(a1, a0);
            float tsel = (a2 < amin) ? tp1 : t01;
            wv[c] = (tsel + 1.0f) * 0.5f * sr + bm;    // mul+add, contract off
        }
        f4 r; r.x = wv[0]; r.y = wv[1]; r.z = wv[2]; r.w = wv[3];
        // output is written once and never re-read — NT store skips
        // write-allocate retention in L2/LLC.
        __builtin_nontemporal_store(r, &out4[k * 64 + lane]);
    }
}

// ---------------------------------------------------------------------------
// Host-side table computation (input-independent, deterministic): f64 ndtri
// via A&S seed + 3 Newton steps on Phi (converges ~1e-13 -> f32 cast is
// libm-variation-proof), f32 normalize, exact fp16 RNE via ulp-scaled rint.
// Same values the passing R5/R6 device path produced.
// ---------------------------------------------------------------------------
static void compute_nf_args(NfArgs* a) {
    double z[16];
    for (int i = 0; i < 16; ++i) {
        double p  = (2.0 * i + 1.0) / 32.0;
        double pl = (p < 0.5) ? p : 1.0 - p;
        double t  = std::sqrt(-2.0 * std::log(pl));
        double zz = t - (2.30753 + 0.27061 * t) / (1.0 + t * (0.99229 + 0.04481 * t));
        if (p < 0.5) zz = -zz;
        for (int it = 0; it < 3; ++it) {
            double Phi = 0.5 * std::erfc(-zz * 0.7071067811865476);
            double phi = 0.3989422804014326779 * std::exp(-0.5 * zz * zz);
            zz -= (Phi - p) / phi;
        }
        z[i] = zz;
    }
    float zf[16], qmax = 0.0f;
    for (int i = 0; i < 16; ++i) { zf[i] = (float)z[i]; qmax = std::fmax(qmax, std::fabs(zf[i])); }
    for (int i = 0; i < 16; ++i) {
        float qn = zf[i] / qmax;                       // IEEE f32 divide
        // exact f32 -> fp16 RNE (values are normal-range fp16)
        double av = std::fabs((double)qn);
        int e; std::frexp(av, &e);
        double ulp = std::ldexp(1.0, e - 11);
        a->tbl[i] = (float)std::copysign(std::rint(av / ulp) * ulp, (double)qn);
    }
    a->kexp = (float)(-1.702 * 1.4426950408889634 * (double)qmax);
}

extern "C" void kernel_launch(void* const* d_in, const int* in_sizes, int n_in,
                              void* d_out, int out_size, void* d_ws, size_t ws_size,
                              hipStream_t stream) {
    const float* x = (const float*)d_in[0];
    float* out     = (float*)d_out;
    const int rows = in_sizes[0] / C_COLS;

    NfArgs args;
    compute_nf_args(&args);                            // host CPU, ~µs, deterministic

    nf4_main_kernel<<<rows, 256, 0, stream>>>(x, out, args);
}